// Round 10
// baseline (587.136 us; speedup 1.0000x reference)
//
#include <hip/hip_runtime.h>
#include <hip/hip_fp16.h>

#define CNUM 29
#define HH 256
#define WW 256
#define BB 2
#define KK 7
#define HALO 3
#define TX 32
#define TY 4
#define LW (TX + 2*HALO)   // 38
#define LH (TY + 2*HALO)   // 10
#define NPIX (LH*LW)       // 380
#define HWP (HH*WW)        // 65536
#define BHWP (BB*HWP)

// 1-D normalized Gaussian, sigma=3.0, K=7 (exp(-d^2/18)/sum)
__device__ constexpr float GW[KK] = {
    0.106287146f, 0.140321912f, 0.165770643f, 0.175240699f,
    0.165770643f, 0.140321912f, 0.106287146f};

__device__ __forceinline__ unsigned packh2(float a, float b) {
    __half2 h = __floats2half2_rn(a, b);
    return *reinterpret_cast<unsigned*>(&h);
}
__device__ __forceinline__ float2 unpkh2(unsigned u) {
    __half2 h = *reinterpret_cast<__half2*>(&u);
    return __half22float2(h);
}

// Accumulate all 29 channels of LDS pixel chunk t4 (swizzle swz) with weight wv.
#define CH_ACCUM(wv)                                                        \
    {                                                                       \
        uint4 q0 = s_q4[t4 + (0 ^ swz)];                                    \
        uint4 q1 = s_q4[t4 + (1 ^ swz)];                                    \
        uint4 q2 = s_q4[t4 + (2 ^ swz)];                                    \
        uint4 q3 = s_q4[t4 + (3 ^ swz)];                                    \
        const unsigned* u0 = &q0.x;                                         \
        const unsigned* u1 = &q1.x;                                         \
        const unsigned* u2 = &q2.x;                                         \
        _Pragma("unroll")                                                   \
        for (int k = 0; k < 4; ++k) {                                       \
            float2 f = unpkh2(u0[k]);                                       \
            acc[2 * k]     += (wv) * f.x;                                   \
            acc[2 * k + 1] += (wv) * f.y;                                   \
        }                                                                   \
        _Pragma("unroll")                                                   \
        for (int k = 0; k < 4; ++k) {                                       \
            float2 f = unpkh2(u1[k]);                                       \
            acc[8 + 2 * k]     += (wv) * f.x;                               \
            acc[8 + 2 * k + 1] += (wv) * f.y;                               \
        }                                                                   \
        _Pragma("unroll")                                                   \
        for (int k = 0; k < 4; ++k) {                                       \
            float2 f = unpkh2(u2[k]);                                       \
            acc[16 + 2 * k]     += (wv) * f.x;                              \
            acc[16 + 2 * k + 1] += (wv) * f.y;                              \
        }                                                                   \
        {                                                                   \
            float2 f = unpkh2(q3.x);                                        \
            acc[24] += (wv) * f.x; acc[25] += (wv) * f.y;                   \
            f = unpkh2(q3.y);                                               \
            acc[26] += (wv) * f.x; acc[27] += (wv) * f.y;                   \
            f = unpkh2(q3.z);                                               \
            acc[28] += (wv) * f.x;                                          \
        }                                                                   \
    }

// One CRF iteration. 256 threads per 32x4 tile (4 blocks/CU), tap-split:
// A-half (tid<128, epilogue owner) does kernel rows 4-6, B-half rows 0-3.
// FIRST: weights computed inline from img AND stored as fp16 into 7 planar
// uint4 planes W[k][b][pix] (A stores planes 4-6, B planes 0-3). Mid iters
// read weights back (coalesced, L3-resident) and never touch img: per-tap
// LDS work is q-only (4x ds_read_b128). uh = packed -unary fp16 from FIRST.
template <bool FIRST, bool LAST>
__global__ __launch_bounds__(256, 4) void crf_iter(const float* __restrict__ unary,
                                                   const float* __restrict__ img,
                                                   const uint4* __restrict__ qin,
                                                   uint4* __restrict__ qout,
                                                   uint4* __restrict__ uh,
                                                   uint4* __restrict__ Wp,
                                                   float* __restrict__ outf) {
    __shared__ uint4 s_q4[NPIX * 4];      // 24,320 B; aliased as partial[29][128]
    __shared__ float s_im[3][NPIX];       //  4,560 B (used only in FIRST)

    const int tid = threadIdx.x;
    const bool isA = tid < 128;           // wave-uniform half; A = epilogue half
    const int lid = tid & 127;
    const int tx = lid & (TX - 1);
    const int ty = lid >> 5;              // 0..3
    const int bx = blockIdx.x * TX;
    const int by = blockIdx.y * TY;
    const int b  = blockIdx.z;
    const int pix = (by + ty) * WW + (bx + tx);

    const float* ubase = unary + (size_t)b * CNUM * HWP;
    const float* imgb  = img + (size_t)b * 3 * HWP;

    // ---- stage ----
    if (FIRST) {
        for (int t = tid; t < NPIX; t += 256) {
            int r = t / LW, cc = t - r * LW;
            int gy = by + r - HALO, gx = bx + cc - HALO;
            bool ok = (gy >= 0) & (gy < HH) & (gx >= 0) & (gx < WW);
            int goff = ok ? gy * WW + gx : 0;
            float i0 = imgb[goff], i1 = imgb[HWP + goff], i2 = imgb[2 * HWP + goff];
            if (!ok) { i0 = 0.f; i1 = 0.f; i2 = 0.f; }
            s_im[0][t] = i0; s_im[1][t] = i1; s_im[2][t] = i2;

            float nu[CNUM];
            float mm = -1e30f;
#pragma unroll
            for (int c = 0; c < CNUM; ++c) {
                nu[c] = -ubase[(size_t)c * HWP + goff];
                mm = fmaxf(mm, nu[c]);
            }
            bool interior = (r >= HALO) & (r < LH - HALO) & (cc >= HALO) & (cc < LW - HALO);
            if (interior) {  // pre-pack -unary fp16 (each pixel owned by one block)
                uint4* up = uh + ((size_t)b * HWP + goff) * 4;
                uint4 u0, u1, u2, u3;
                u0.x = packh2(nu[0],  nu[1]);  u0.y = packh2(nu[2],  nu[3]);
                u0.z = packh2(nu[4],  nu[5]);  u0.w = packh2(nu[6],  nu[7]);
                u1.x = packh2(nu[8],  nu[9]);  u1.y = packh2(nu[10], nu[11]);
                u1.z = packh2(nu[12], nu[13]); u1.w = packh2(nu[14], nu[15]);
                u2.x = packh2(nu[16], nu[17]); u2.y = packh2(nu[18], nu[19]);
                u2.z = packh2(nu[20], nu[21]); u2.w = packh2(nu[22], nu[23]);
                u3.x = packh2(nu[24], nu[25]); u3.y = packh2(nu[26], nu[27]);
                u3.z = packh2(nu[28], 0.f);    u3.w = 0u;
                up[0] = u0; up[1] = u1; up[2] = u2; up[3] = u3;
            }
            float ss = 0.f;
            float v[CNUM];
#pragma unroll
            for (int c = 0; c < CNUM; ++c) { v[c] = __expf(nu[c] - mm); ss += v[c]; }
            float inv = ok ? 1.f / ss : 0.f;
#pragma unroll
            for (int c = 0; c < CNUM; ++c) v[c] *= inv;
            const int swz = (t >> 1) & 3;
            uint4 p0, p1, p2, p3;
            p0.x = packh2(v[0],  v[1]);  p0.y = packh2(v[2],  v[3]);
            p0.z = packh2(v[4],  v[5]);  p0.w = packh2(v[6],  v[7]);
            p1.x = packh2(v[8],  v[9]);  p1.y = packh2(v[10], v[11]);
            p1.z = packh2(v[12], v[13]); p1.w = packh2(v[14], v[15]);
            p2.x = packh2(v[16], v[17]); p2.y = packh2(v[18], v[19]);
            p2.z = packh2(v[20], v[21]); p2.w = packh2(v[22], v[23]);
            p3.x = packh2(v[24], v[25]); p3.y = packh2(v[26], v[27]);
            p3.z = packh2(v[28], 0.f);   p3.w = 0u;
            s_q4[t * 4 + (0 ^ swz)] = p0;
            s_q4[t * 4 + (1 ^ swz)] = p1;
            s_q4[t * 4 + (2 ^ swz)] = p2;
            s_q4[t * 4 + (3 ^ swz)] = p3;
        }
    } else {
        // q-only stage, both rounds' loads issued before LDS writes
        int t = tid;
        int r = t / LW, cc = t - r * LW;
        int gy = by + r - HALO, gx = bx + cc - HALO;
        bool ok = (gy >= 0) & (gy < HH) & (gx >= 0) & (gx < WW);
        int goff = ok ? gy * WW + gx : 0;
        const uint4* qp = qin + ((size_t)b * HWP + goff) * 4;
        uint4 p0 = qp[0], p1 = qp[1], p2 = qp[2], p3 = qp[3];

        int t2 = tid + 256;
        bool has2 = t2 < NPIX;
        int r2 = t2 / LW, cc2 = t2 - r2 * LW;
        int gy2 = by + r2 - HALO, gx2 = bx + cc2 - HALO;
        bool ok2 = has2 & (gy2 >= 0) & (gy2 < HH) & (gx2 >= 0) & (gx2 < WW);
        int goff2 = ok2 ? gy2 * WW + gx2 : 0;
        uint4 s0, s1, s2, s3;
        if (has2) {
            const uint4* qp2 = qin + ((size_t)b * HWP + goff2) * 4;
            s0 = qp2[0]; s1 = qp2[1]; s2 = qp2[2]; s3 = qp2[3];
        }
        if (!ok) {
            p0.x = p0.y = p0.z = p0.w = 0u; p1.x = p1.y = p1.z = p1.w = 0u;
            p2.x = p2.y = p2.z = p2.w = 0u; p3.x = p3.y = p3.z = p3.w = 0u;
        }
        const int swz = (t >> 1) & 3;
        s_q4[t * 4 + (0 ^ swz)] = p0;
        s_q4[t * 4 + (1 ^ swz)] = p1;
        s_q4[t * 4 + (2 ^ swz)] = p2;
        s_q4[t * 4 + (3 ^ swz)] = p3;
        if (has2) {
            if (!ok2) {
                s0.x = s0.y = s0.z = s0.w = 0u; s1.x = s1.y = s1.z = s1.w = 0u;
                s2.x = s2.y = s2.z = s2.w = 0u; s3.x = s3.y = s3.z = s3.w = 0u;
            }
            const int swz2 = (t2 >> 1) & 3;
            s_q4[t2 * 4 + (0 ^ swz2)] = s0;
            s_q4[t2 * 4 + (1 ^ swz2)] = s1;
            s_q4[t2 * 4 + (2 ^ swz2)] = s2;
            s_q4[t2 * 4 + (3 ^ swz2)] = s3;
        }
    }

    // ---- hoisted global loads for tap/epilogue (mid iters) ----
    uint4 wk[4];
    uint4 un0, un1, un2, un3;
    if (!FIRST) {
        const uint4* wb = Wp + (size_t)b * HWP + pix;
        if (isA) {   // planes 4-6 (rows 4-6) + uh for epilogue
            wk[0] = wb[(size_t)4 * BHWP];
            wk[1] = wb[(size_t)5 * BHWP];
            wk[2] = wb[(size_t)6 * BHWP];
            const uint4* up = uh + ((size_t)b * HWP + pix) * 4;
            un0 = up[0]; un1 = up[1]; un2 = up[2]; un3 = up[3];
        } else {     // planes 0-3 (rows 0-3)
            wk[0] = wb[0];
            wk[1] = wb[(size_t)1 * BHWP];
            wk[2] = wb[(size_t)2 * BHWP];
            wk[3] = wb[(size_t)3 * BHWP];
        }
    }
    __syncthreads();

    // ---- tap phase ----
    float acc[CNUM];
#pragma unroll
    for (int c = 0; c < CNUM; ++c) acc[c] = 0.f;

    if (FIRST) {
        const int tc = (ty + HALO) * LW + (tx + HALO);
        const float c0 = s_im[0][tc];
        const float c1 = s_im[1][tc];
        const float c2 = s_im[2][tc];
        uint4* wb = Wp + (size_t)b * HWP + pix;
        if (isA) {
            unsigned wst[12] = {0};
#pragma unroll
            for (int i = 4; i < KK; ++i)
#pragma unroll
                for (int j = 0; j < KK; ++j) {
                    const int t = (ty + i) * LW + (tx + j);
                    float d0 = s_im[0][t] - c0;
                    float d1 = s_im[1][t] - c1;
                    float d2 = s_im[2][t] - c2;
                    float dsq = d0 * d0 + d1 * d1 + d2 * d2;
                    float w = (GW[i] * GW[j]) * (3.0f + 10.0f * __expf(dsq * -0.005f));
                    const int idxL = (i - 4) * 7 + j;
                    unsigned hw = (unsigned)__half_as_ushort(__float2half_rn(w));
                    if ((idxL & 1) == 0) wst[idxL >> 1] = hw;
                    else                 wst[idxL >> 1] |= hw << 16;
                    const int t4 = t * 4;
                    const int swz = (t >> 1) & 3;
                    CH_ACCUM(w)
                }
            uint4 o;
            o.x = wst[0]; o.y = wst[1]; o.z = wst[2];  o.w = wst[3];  wb[(size_t)4 * BHWP] = o;
            o.x = wst[4]; o.y = wst[5]; o.z = wst[6];  o.w = wst[7];  wb[(size_t)5 * BHWP] = o;
            o.x = wst[8]; o.y = wst[9]; o.z = wst[10]; o.w = wst[11]; wb[(size_t)6 * BHWP] = o;
        } else {
            unsigned wst[16] = {0};
#pragma unroll
            for (int i = 0; i < 4; ++i)
#pragma unroll
                for (int j = 0; j < KK; ++j) {
                    const int t = (ty + i) * LW + (tx + j);
                    float d0 = s_im[0][t] - c0;
                    float d1 = s_im[1][t] - c1;
                    float d2 = s_im[2][t] - c2;
                    float dsq = d0 * d0 + d1 * d1 + d2 * d2;
                    float w = (GW[i] * GW[j]) * (3.0f + 10.0f * __expf(dsq * -0.005f));
                    const int idx = i * 7 + j;
                    unsigned hw = (unsigned)__half_as_ushort(__float2half_rn(w));
                    if ((idx & 1) == 0) wst[idx >> 1] = hw;
                    else                wst[idx >> 1] |= hw << 16;
                    const int t4 = t * 4;
                    const int swz = (t >> 1) & 3;
                    CH_ACCUM(w)
                }
            uint4 o;
            o.x = wst[0];  o.y = wst[1];  o.z = wst[2];  o.w = wst[3];  wb[0] = o;
            o.x = wst[4];  o.y = wst[5];  o.z = wst[6];  o.w = wst[7];  wb[(size_t)1 * BHWP] = o;
            o.x = wst[8];  o.y = wst[9];  o.z = wst[10]; o.w = wst[11]; wb[(size_t)2 * BHWP] = o;
            o.x = wst[12]; o.y = wst[13]; o.z = wst[14]; o.w = wst[15]; wb[(size_t)3 * BHWP] = o;
        }
    } else {
        if (isA) {
#pragma unroll
            for (int i = 4; i < KK; ++i)
#pragma unroll
                for (int j = 0; j < KK; ++j) {
                    const int idxL = (i - 4) * 7 + j;
                    const unsigned ww = (&wk[idxL >> 3].x)[(idxL >> 1) & 3];
                    const float w = __half2float(__ushort_as_half(
                        (unsigned short)((idxL & 1) ? (ww >> 16) : (ww & 0xffffu))));
                    const int t = (ty + i) * LW + (tx + j);
                    const int t4 = t * 4;
                    const int swz = (t >> 1) & 3;
                    CH_ACCUM(w)
                }
        } else {
#pragma unroll
            for (int i = 0; i < 4; ++i)
#pragma unroll
                for (int j = 0; j < KK; ++j) {
                    const int idx = i * 7 + j;
                    const unsigned ww = (&wk[idx >> 3].x)[(idx >> 1) & 3];
                    const float w = __half2float(__ushort_as_half(
                        (unsigned short)((idx & 1) ? (ww >> 16) : (ww & 0xffffu))));
                    const int t = (ty + i) * LW + (tx + j);
                    const int t4 = t * 4;
                    const int swz = (t >> 1) & 3;
                    CH_ACCUM(w)
                }
        }
    }

    // ---- join partials: B writes [c][lid], A adds ----
    __syncthreads();                     // all s_q4 tap reads complete
    float* s_part = reinterpret_cast<float*>(s_q4);   // 29*128*4 B fits
    if (!isA) {
#pragma unroll
        for (int c = 0; c < CNUM; ++c) s_part[c * 128 + lid] = acc[c];
    }
    __syncthreads();

    if (isA) {
        float l[CNUM];
        if (FIRST) {
#pragma unroll
            for (int c = 0; c < CNUM; ++c)
                l[c] = acc[c] + s_part[c * 128 + lid] - ubase[(size_t)c * HWP + pix];
        } else {
            const unsigned* w0 = &un0.x;
            const unsigned* w1 = &un1.x;
            const unsigned* w2 = &un2.x;
            float nu[CNUM];
#pragma unroll
            for (int k = 0; k < 4; ++k) {
                float2 f = unpkh2(w0[k]); nu[2 * k] = f.x; nu[2 * k + 1] = f.y;
            }
#pragma unroll
            for (int k = 0; k < 4; ++k) {
                float2 f = unpkh2(w1[k]); nu[8 + 2 * k] = f.x; nu[8 + 2 * k + 1] = f.y;
            }
#pragma unroll
            for (int k = 0; k < 4; ++k) {
                float2 f = unpkh2(w2[k]); nu[16 + 2 * k] = f.x; nu[16 + 2 * k + 1] = f.y;
            }
            { float2 f = unpkh2(un3.x); nu[24] = f.x; nu[25] = f.y; }
            { float2 f = unpkh2(un3.y); nu[26] = f.x; nu[27] = f.y; }
            { float2 f = unpkh2(un3.z); nu[28] = f.x; }
#pragma unroll
            for (int c = 0; c < CNUM; ++c)
                l[c] = acc[c] + s_part[c * 128 + lid] + nu[c];
        }
        float m = l[0];
#pragma unroll
        for (int c = 1; c < CNUM; ++c) m = fmaxf(m, l[c]);
        float ss = 0.f;
#pragma unroll
        for (int c = 0; c < CNUM; ++c) { l[c] = __expf(l[c] - m); ss += l[c]; }
        float inv = 1.0f / ss;

        if (LAST) {
            float* qo = outf + (size_t)b * CNUM * HWP + pix;
#pragma unroll
            for (int c = 0; c < CNUM; ++c) qo[(size_t)c * HWP] = l[c] * inv;
        } else {
            uint4 p0, p1, p2, p3;
            p0.x = packh2(l[0] * inv,  l[1] * inv);
            p0.y = packh2(l[2] * inv,  l[3] * inv);
            p0.z = packh2(l[4] * inv,  l[5] * inv);
            p0.w = packh2(l[6] * inv,  l[7] * inv);
            p1.x = packh2(l[8] * inv,  l[9] * inv);
            p1.y = packh2(l[10] * inv, l[11] * inv);
            p1.z = packh2(l[12] * inv, l[13] * inv);
            p1.w = packh2(l[14] * inv, l[15] * inv);
            p2.x = packh2(l[16] * inv, l[17] * inv);
            p2.y = packh2(l[18] * inv, l[19] * inv);
            p2.z = packh2(l[20] * inv, l[21] * inv);
            p2.w = packh2(l[22] * inv, l[23] * inv);
            p3.x = packh2(l[24] * inv, l[25] * inv);
            p3.y = packh2(l[26] * inv, l[27] * inv);
            p3.z = packh2(l[28] * inv, 0.f);
            p3.w = 0u;
            uint4* qo = qout + ((size_t)b * HWP + pix) * 4;
            qo[0] = p0; qo[1] = p1; qo[2] = p2; qo[3] = p3;
        }
    }
}

extern "C" void kernel_launch(void* const* d_in, const int* in_sizes, int n_in,
                              void* d_out, int out_size, void* d_ws, size_t ws_size,
                              hipStream_t stream) {
    const float* unary = (const float*)d_in[0];
    const float* img   = (const float*)d_in[1];
    // ws: qA (8.39MB) | qB (8.39MB) | uh (8.39MB) | W (14.68MB) = 39.8 MB
    const size_t QBYTES = (size_t)BB * HWP * 64;
    uint4* qA = (uint4*)d_ws;
    uint4* qB = (uint4*)((char*)d_ws + QBYTES);
    uint4* uh = (uint4*)((char*)d_ws + 2 * QBYTES);
    uint4* Wp = (uint4*)((char*)d_ws + 3 * QBYTES);
    float* outf = (float*)d_out;

    dim3 grid(WW / TX, HH / TY, BB);   // (8, 64, 2) = 1024 blocks
    crf_iter<true,  false><<<grid, 256, 0, stream>>>(unary, img, qB, qA, uh, Wp, outf); // i1 -> qA
    crf_iter<false, false><<<grid, 256, 0, stream>>>(unary, img, qA, qB, uh, Wp, outf); // i2
    crf_iter<false, false><<<grid, 256, 0, stream>>>(unary, img, qB, qA, uh, Wp, outf); // i3
    crf_iter<false, false><<<grid, 256, 0, stream>>>(unary, img, qA, qB, uh, Wp, outf); // i4
    crf_iter<false, true ><<<grid, 256, 0, stream>>>(unary, img, qB, qA, uh, Wp, outf); // i5 -> d_out
}

// Round 11
// 173.584 us; speedup vs baseline: 3.3824x; 3.3824x over previous
//
#include <hip/hip_runtime.h>
#include <hip/hip_fp16.h>

#define CNUM 29
#define HH 256
#define WW 256
#define BB 2
#define KK 7
#define HALO 3
#define TX 32
#define TY 4
#define LW (TX + 2*HALO)   // 38
#define LH (TY + 2*HALO)   // 10
#define NPIX (LH*LW)       // 380
#define HWP (HH*WW)        // 65536
#define BHWP (BB*HWP)

// 1-D normalized Gaussian, sigma=3.0, K=7 (exp(-d^2/18)/sum)
__device__ constexpr float GW[KK] = {
    0.106287146f, 0.140321912f, 0.165770643f, 0.175240699f,
    0.165770643f, 0.140321912f, 0.106287146f};

__device__ __forceinline__ unsigned packh2(float a, float b) {
    __half2 h = __floats2half2_rn(a, b);
    return *reinterpret_cast<unsigned*>(&h);
}
__device__ __forceinline__ float2 unpkh2(unsigned u) {
    __half2 h = *reinterpret_cast<__half2*>(&u);
    return __half22float2(h);
}

// Accumulate all 29 channels of LDS pixel chunk t4 (swizzle swz) with weight wv.
#define CH_ACCUM(wgt)                                                       \
    {                                                                       \
        uint4 q0 = s_q4[t4 + (0 ^ swz)];                                    \
        uint4 q1 = s_q4[t4 + (1 ^ swz)];                                    \
        uint4 q2 = s_q4[t4 + (2 ^ swz)];                                    \
        uint4 q3 = s_q4[t4 + (3 ^ swz)];                                    \
        const unsigned* u0 = &q0.x;                                         \
        const unsigned* u1 = &q1.x;                                         \
        const unsigned* u2 = &q2.x;                                         \
        _Pragma("unroll")                                                   \
        for (int k = 0; k < 4; ++k) {                                       \
            float2 f = unpkh2(u0[k]);                                       \
            acc[2 * k]     += (wgt) * f.x;                                  \
            acc[2 * k + 1] += (wgt) * f.y;                                  \
        }                                                                   \
        _Pragma("unroll")                                                   \
        for (int k = 0; k < 4; ++k) {                                       \
            float2 f = unpkh2(u1[k]);                                       \
            acc[8 + 2 * k]     += (wgt) * f.x;                              \
            acc[8 + 2 * k + 1] += (wgt) * f.y;                              \
        }                                                                   \
        _Pragma("unroll")                                                   \
        for (int k = 0; k < 4; ++k) {                                       \
            float2 f = unpkh2(u2[k]);                                       \
            acc[16 + 2 * k]     += (wgt) * f.x;                             \
            acc[16 + 2 * k + 1] += (wgt) * f.y;                             \
        }                                                                   \
        {                                                                   \
            float2 f = unpkh2(q3.x);                                        \
            acc[24] += (wgt) * f.x; acc[25] += (wgt) * f.y;                 \
            f = unpkh2(q3.y);                                               \
            acc[26] += (wgt) * f.x; acc[27] += (wgt) * f.y;                 \
            f = unpkh2(q3.z);                                               \
            acc[28] += (wgt) * f.x;                                         \
        }                                                                   \
    }

// One CRF iteration. 256 threads per 32x4 tile, tap-split: A-half (tid<128,
// epilogue owner) does kernel rows 4-6 (21 taps), B-half rows 0-3 (28 taps).
// FIRST: weights computed inline from img AND stored fp16 into 7 planar uint4
// planes W[k][b][pix] (A stores planes 4-6, B planes 0-3). Mid iters read
// weights back (coalesced, L2/L3-resident) and never touch img: per-tap LDS
// work is q-only (4x ds_read_b128). uh = packed -unary fp16 from FIRST.
// NOTE: no min-occupancy launch bound — round 10 proved forcing one spills.
template <bool FIRST, bool LAST>
__global__ __launch_bounds__(256) void crf_iter(const float* __restrict__ unary,
                                                const float* __restrict__ img,
                                                const uint4* __restrict__ qin,
                                                uint4* __restrict__ qout,
                                                uint4* __restrict__ uh,
                                                uint4* __restrict__ Wp,
                                                float* __restrict__ outf) {
    __shared__ uint4 s_q4[NPIX * 4];      // 24,320 B; aliased as partial[29][128]
    __shared__ float s_im[3][NPIX];       //  4,560 B (used only in FIRST)

    const int tid = threadIdx.x;
    const bool isA = tid < 128;           // wave-uniform half; A = epilogue half
    const int lid = tid & 127;
    const int tx = lid & (TX - 1);
    const int ty = lid >> 5;              // 0..3
    const int bx = blockIdx.x * TX;
    const int by = blockIdx.y * TY;
    const int b  = blockIdx.z;
    const int pix = (by + ty) * WW + (bx + tx);

    const float* ubase = unary + (size_t)b * CNUM * HWP;
    const float* imgb  = img + (size_t)b * 3 * HWP;

    // ---- stage ----
    if (FIRST) {
        for (int t = tid; t < NPIX; t += 256) {
            int r = t / LW, cc = t - r * LW;
            int gy = by + r - HALO, gx = bx + cc - HALO;
            bool ok = (gy >= 0) & (gy < HH) & (gx >= 0) & (gx < WW);
            int goff = ok ? gy * WW + gx : 0;
            float i0 = imgb[goff], i1 = imgb[HWP + goff], i2 = imgb[2 * HWP + goff];
            if (!ok) { i0 = 0.f; i1 = 0.f; i2 = 0.f; }
            s_im[0][t] = i0; s_im[1][t] = i1; s_im[2][t] = i2;

            float nu[CNUM];
            float mm = -1e30f;
#pragma unroll
            for (int c = 0; c < CNUM; ++c) {
                nu[c] = -ubase[(size_t)c * HWP + goff];
                mm = fmaxf(mm, nu[c]);
            }
            bool interior = (r >= HALO) & (r < LH - HALO) & (cc >= HALO) & (cc < LW - HALO);
            if (interior) {  // pre-pack -unary fp16 (each pixel owned by one block)
                uint4* up = uh + ((size_t)b * HWP + goff) * 4;
                uint4 u0, u1, u2, u3;
                u0.x = packh2(nu[0],  nu[1]);  u0.y = packh2(nu[2],  nu[3]);
                u0.z = packh2(nu[4],  nu[5]);  u0.w = packh2(nu[6],  nu[7]);
                u1.x = packh2(nu[8],  nu[9]);  u1.y = packh2(nu[10], nu[11]);
                u1.z = packh2(nu[12], nu[13]); u1.w = packh2(nu[14], nu[15]);
                u2.x = packh2(nu[16], nu[17]); u2.y = packh2(nu[18], nu[19]);
                u2.z = packh2(nu[20], nu[21]); u2.w = packh2(nu[22], nu[23]);
                u3.x = packh2(nu[24], nu[25]); u3.y = packh2(nu[26], nu[27]);
                u3.z = packh2(nu[28], 0.f);    u3.w = 0u;
                up[0] = u0; up[1] = u1; up[2] = u2; up[3] = u3;
            }
            float ss = 0.f;
            float v[CNUM];
#pragma unroll
            for (int c = 0; c < CNUM; ++c) { v[c] = __expf(nu[c] - mm); ss += v[c]; }
            float inv = ok ? 1.f / ss : 0.f;
#pragma unroll
            for (int c = 0; c < CNUM; ++c) v[c] *= inv;
            const int swz = (t >> 1) & 3;
            uint4 p0, p1, p2, p3;
            p0.x = packh2(v[0],  v[1]);  p0.y = packh2(v[2],  v[3]);
            p0.z = packh2(v[4],  v[5]);  p0.w = packh2(v[6],  v[7]);
            p1.x = packh2(v[8],  v[9]);  p1.y = packh2(v[10], v[11]);
            p1.z = packh2(v[12], v[13]); p1.w = packh2(v[14], v[15]);
            p2.x = packh2(v[16], v[17]); p2.y = packh2(v[18], v[19]);
            p2.z = packh2(v[20], v[21]); p2.w = packh2(v[22], v[23]);
            p3.x = packh2(v[24], v[25]); p3.y = packh2(v[26], v[27]);
            p3.z = packh2(v[28], 0.f);   p3.w = 0u;
            s_q4[t * 4 + (0 ^ swz)] = p0;
            s_q4[t * 4 + (1 ^ swz)] = p1;
            s_q4[t * 4 + (2 ^ swz)] = p2;
            s_q4[t * 4 + (3 ^ swz)] = p3;
        }
    } else {
        // q-only stage, both rounds' loads issued before LDS writes
        int t = tid;
        int r = t / LW, cc = t - r * LW;
        int gy = by + r - HALO, gx = bx + cc - HALO;
        bool ok = (gy >= 0) & (gy < HH) & (gx >= 0) & (gx < WW);
        int goff = ok ? gy * WW + gx : 0;
        const uint4* qp = qin + ((size_t)b * HWP + goff) * 4;
        uint4 p0 = qp[0], p1 = qp[1], p2 = qp[2], p3 = qp[3];

        int t2 = tid + 256;
        bool has2 = t2 < NPIX;
        int r2 = t2 / LW, cc2 = t2 - r2 * LW;
        int gy2 = by + r2 - HALO, gx2 = bx + cc2 - HALO;
        bool ok2 = has2 & (gy2 >= 0) & (gy2 < HH) & (gx2 >= 0) & (gx2 < WW);
        int goff2 = ok2 ? gy2 * WW + gx2 : 0;
        uint4 s0, s1, s2, s3;
        if (has2) {
            const uint4* qp2 = qin + ((size_t)b * HWP + goff2) * 4;
            s0 = qp2[0]; s1 = qp2[1]; s2 = qp2[2]; s3 = qp2[3];
        }
        if (!ok) {
            p0.x = p0.y = p0.z = p0.w = 0u; p1.x = p1.y = p1.z = p1.w = 0u;
            p2.x = p2.y = p2.z = p2.w = 0u; p3.x = p3.y = p3.z = p3.w = 0u;
        }
        const int swz = (t >> 1) & 3;
        s_q4[t * 4 + (0 ^ swz)] = p0;
        s_q4[t * 4 + (1 ^ swz)] = p1;
        s_q4[t * 4 + (2 ^ swz)] = p2;
        s_q4[t * 4 + (3 ^ swz)] = p3;
        if (has2) {
            if (!ok2) {
                s0.x = s0.y = s0.z = s0.w = 0u; s1.x = s1.y = s1.z = s1.w = 0u;
                s2.x = s2.y = s2.z = s2.w = 0u; s3.x = s3.y = s3.z = s3.w = 0u;
            }
            const int swz2 = (t2 >> 1) & 3;
            s_q4[t2 * 4 + (0 ^ swz2)] = s0;
            s_q4[t2 * 4 + (1 ^ swz2)] = s1;
            s_q4[t2 * 4 + (2 ^ swz2)] = s2;
            s_q4[t2 * 4 + (3 ^ swz2)] = s3;
        }
    }

    // ---- hoisted global loads for tap/epilogue (mid iters) ----
    // Flat unsigned array with only compile-time indices -> stays in VGPRs.
    unsigned wv[16];
    uint4 un0, un1, un2, un3;
    if (!FIRST) {
        const uint4* wb = Wp + (size_t)b * HWP + pix;
        if (isA) {   // planes 4-6 (rows 4-6, 21 taps -> 12 u32) + uh for epilogue
            uint4 a0 = wb[(size_t)4 * BHWP];
            uint4 a1 = wb[(size_t)5 * BHWP];
            uint4 a2 = wb[(size_t)6 * BHWP];
            wv[0] = a0.x;  wv[1] = a0.y;  wv[2]  = a0.z;  wv[3]  = a0.w;
            wv[4] = a1.x;  wv[5] = a1.y;  wv[6]  = a1.z;  wv[7]  = a1.w;
            wv[8] = a2.x;  wv[9] = a2.y;  wv[10] = a2.z;  wv[11] = a2.w;
            const uint4* up = uh + ((size_t)b * HWP + pix) * 4;
            un0 = up[0]; un1 = up[1]; un2 = up[2]; un3 = up[3];
        } else {     // planes 0-3 (rows 0-3, 28 taps -> 14 u32)
            uint4 a0 = wb[0];
            uint4 a1 = wb[(size_t)1 * BHWP];
            uint4 a2 = wb[(size_t)2 * BHWP];
            uint4 a3 = wb[(size_t)3 * BHWP];
            wv[0]  = a0.x; wv[1]  = a0.y; wv[2]  = a0.z; wv[3]  = a0.w;
            wv[4]  = a1.x; wv[5]  = a1.y; wv[6]  = a1.z; wv[7]  = a1.w;
            wv[8]  = a2.x; wv[9]  = a2.y; wv[10] = a2.z; wv[11] = a2.w;
            wv[12] = a3.x; wv[13] = a3.y; wv[14] = a3.z; wv[15] = a3.w;
        }
    }
    __syncthreads();

    // ---- tap phase ----
    float acc[CNUM];
#pragma unroll
    for (int c = 0; c < CNUM; ++c) acc[c] = 0.f;

    if (FIRST) {
        const int tc = (ty + HALO) * LW + (tx + HALO);
        const float c0 = s_im[0][tc];
        const float c1 = s_im[1][tc];
        const float c2 = s_im[2][tc];
        uint4* wb = Wp + (size_t)b * HWP + pix;
        if (isA) {
            unsigned wst[12] = {0};
#pragma unroll
            for (int i = 4; i < KK; ++i)
#pragma unroll
                for (int j = 0; j < KK; ++j) {
                    const int t = (ty + i) * LW + (tx + j);
                    float d0 = s_im[0][t] - c0;
                    float d1 = s_im[1][t] - c1;
                    float d2 = s_im[2][t] - c2;
                    float dsq = d0 * d0 + d1 * d1 + d2 * d2;
                    float w = (GW[i] * GW[j]) * (3.0f + 10.0f * __expf(dsq * -0.005f));
                    const int idx = (i - 4) * 7 + j;
                    unsigned hw = (unsigned)__half_as_ushort(__float2half_rn(w));
                    if ((idx & 1) == 0) wst[idx >> 1] = hw;
                    else                wst[idx >> 1] |= hw << 16;
                    const int t4 = t * 4;
                    const int swz = (t >> 1) & 3;
                    CH_ACCUM(w)
                }
            uint4 o;
            o.x = wst[0]; o.y = wst[1]; o.z = wst[2];  o.w = wst[3];  wb[(size_t)4 * BHWP] = o;
            o.x = wst[4]; o.y = wst[5]; o.z = wst[6];  o.w = wst[7];  wb[(size_t)5 * BHWP] = o;
            o.x = wst[8]; o.y = wst[9]; o.z = wst[10]; o.w = wst[11]; wb[(size_t)6 * BHWP] = o;
        } else {
            unsigned wst[16] = {0};
#pragma unroll
            for (int i = 0; i < 4; ++i)
#pragma unroll
                for (int j = 0; j < KK; ++j) {
                    const int t = (ty + i) * LW + (tx + j);
                    float d0 = s_im[0][t] - c0;
                    float d1 = s_im[1][t] - c1;
                    float d2 = s_im[2][t] - c2;
                    float dsq = d0 * d0 + d1 * d1 + d2 * d2;
                    float w = (GW[i] * GW[j]) * (3.0f + 10.0f * __expf(dsq * -0.005f));
                    const int idx = i * 7 + j;
                    unsigned hw = (unsigned)__half_as_ushort(__float2half_rn(w));
                    if ((idx & 1) == 0) wst[idx >> 1] = hw;
                    else                wst[idx >> 1] |= hw << 16;
                    const int t4 = t * 4;
                    const int swz = (t >> 1) & 3;
                    CH_ACCUM(w)
                }
            uint4 o;
            o.x = wst[0];  o.y = wst[1];  o.z = wst[2];  o.w = wst[3];  wb[0] = o;
            o.x = wst[4];  o.y = wst[5];  o.z = wst[6];  o.w = wst[7];  wb[(size_t)1 * BHWP] = o;
            o.x = wst[8];  o.y = wst[9];  o.z = wst[10]; o.w = wst[11]; wb[(size_t)2 * BHWP] = o;
            o.x = wst[12]; o.y = wst[13]; o.z = wst[14]; o.w = wst[15]; wb[(size_t)3 * BHWP] = o;
        }
    } else {
        if (isA) {
#pragma unroll
            for (int i = 4; i < KK; ++i)
#pragma unroll
                for (int j = 0; j < KK; ++j) {
                    const int idx = (i - 4) * 7 + j;
                    const unsigned ww = wv[idx >> 1];
                    const float w = __half2float(__ushort_as_half(
                        (unsigned short)((idx & 1) ? (ww >> 16) : (ww & 0xffffu))));
                    const int t = (ty + i) * LW + (tx + j);
                    const int t4 = t * 4;
                    const int swz = (t >> 1) & 3;
                    CH_ACCUM(w)
                }
        } else {
#pragma unroll
            for (int i = 0; i < 4; ++i)
#pragma unroll
                for (int j = 0; j < KK; ++j) {
                    const int idx = i * 7 + j;
                    const unsigned ww = wv[idx >> 1];
                    const float w = __half2float(__ushort_as_half(
                        (unsigned short)((idx & 1) ? (ww >> 16) : (ww & 0xffffu))));
                    const int t = (ty + i) * LW + (tx + j);
                    const int t4 = t * 4;
                    const int swz = (t >> 1) & 3;
                    CH_ACCUM(w)
                }
        }
    }

    // ---- join partials: B writes [c][lid], A adds ----
    __syncthreads();                     // all s_q4 tap reads complete
    float* s_part = reinterpret_cast<float*>(s_q4);   // 29*128*4 B fits
    if (!isA) {
#pragma unroll
        for (int c = 0; c < CNUM; ++c) s_part[c * 128 + lid] = acc[c];
    }
    __syncthreads();

    if (isA) {
        float l[CNUM];
        if (FIRST) {
#pragma unroll
            for (int c = 0; c < CNUM; ++c)
                l[c] = acc[c] + s_part[c * 128 + lid] - ubase[(size_t)c * HWP + pix];
        } else {
            const unsigned* w0 = &un0.x;
            const unsigned* w1 = &un1.x;
            const unsigned* w2 = &un2.x;
            float nu[CNUM];
#pragma unroll
            for (int k = 0; k < 4; ++k) {
                float2 f = unpkh2(w0[k]); nu[2 * k] = f.x; nu[2 * k + 1] = f.y;
            }
#pragma unroll
            for (int k = 0; k < 4; ++k) {
                float2 f = unpkh2(w1[k]); nu[8 + 2 * k] = f.x; nu[8 + 2 * k + 1] = f.y;
            }
#pragma unroll
            for (int k = 0; k < 4; ++k) {
                float2 f = unpkh2(w2[k]); nu[16 + 2 * k] = f.x; nu[16 + 2 * k + 1] = f.y;
            }
            { float2 f = unpkh2(un3.x); nu[24] = f.x; nu[25] = f.y; }
            { float2 f = unpkh2(un3.y); nu[26] = f.x; nu[27] = f.y; }
            { float2 f = unpkh2(un3.z); nu[28] = f.x; }
#pragma unroll
            for (int c = 0; c < CNUM; ++c)
                l[c] = acc[c] + s_part[c * 128 + lid] + nu[c];
        }
        float m = l[0];
#pragma unroll
        for (int c = 1; c < CNUM; ++c) m = fmaxf(m, l[c]);
        float ss = 0.f;
#pragma unroll
        for (int c = 0; c < CNUM; ++c) { l[c] = __expf(l[c] - m); ss += l[c]; }
        float inv = 1.0f / ss;

        if (LAST) {
            float* qo = outf + (size_t)b * CNUM * HWP + pix;
#pragma unroll
            for (int c = 0; c < CNUM; ++c) qo[(size_t)c * HWP] = l[c] * inv;
        } else {
            uint4 p0, p1, p2, p3;
            p0.x = packh2(l[0] * inv,  l[1] * inv);
            p0.y = packh2(l[2] * inv,  l[3] * inv);
            p0.z = packh2(l[4] * inv,  l[5] * inv);
            p0.w = packh2(l[6] * inv,  l[7] * inv);
            p1.x = packh2(l[8] * inv,  l[9] * inv);
            p1.y = packh2(l[10] * inv, l[11] * inv);
            p1.z = packh2(l[12] * inv, l[13] * inv);
            p1.w = packh2(l[14] * inv, l[15] * inv);
            p2.x = packh2(l[16] * inv, l[17] * inv);
            p2.y = packh2(l[18] * inv, l[19] * inv);
            p2.z = packh2(l[20] * inv, l[21] * inv);
            p2.w = packh2(l[22] * inv, l[23] * inv);
            p3.x = packh2(l[24] * inv, l[25] * inv);
            p3.y = packh2(l[26] * inv, l[27] * inv);
            p3.z = packh2(l[28] * inv, 0.f);
            p3.w = 0u;
            uint4* qo = qout + ((size_t)b * HWP + pix) * 4;
            qo[0] = p0; qo[1] = p1; qo[2] = p2; qo[3] = p3;
        }
    }
}

extern "C" void kernel_launch(void* const* d_in, const int* in_sizes, int n_in,
                              void* d_out, int out_size, void* d_ws, size_t ws_size,
                              hipStream_t stream) {
    const float* unary = (const float*)d_in[0];
    const float* img   = (const float*)d_in[1];
    // ws: qA (8.39MB) | qB (8.39MB) | uh (8.39MB) | W (14.68MB) = 39.8 MB
    const size_t QBYTES = (size_t)BB * HWP * 64;
    uint4* qA = (uint4*)d_ws;
    uint4* qB = (uint4*)((char*)d_ws + QBYTES);
    uint4* uh = (uint4*)((char*)d_ws + 2 * QBYTES);
    uint4* Wp = (uint4*)((char*)d_ws + 3 * QBYTES);
    float* outf = (float*)d_out;

    dim3 grid(WW / TX, HH / TY, BB);   // (8, 64, 2) = 1024 blocks
    crf_iter<true,  false><<<grid, 256, 0, stream>>>(unary, img, qB, qA, uh, Wp, outf); // i1 -> qA
    crf_iter<false, false><<<grid, 256, 0, stream>>>(unary, img, qA, qB, uh, Wp, outf); // i2
    crf_iter<false, false><<<grid, 256, 0, stream>>>(unary, img, qB, qA, uh, Wp, outf); // i3
    crf_iter<false, false><<<grid, 256, 0, stream>>>(unary, img, qA, qB, uh, Wp, outf); // i4
    crf_iter<false, true ><<<grid, 256, 0, stream>>>(unary, img, qB, qA, uh, Wp, outf); // i5 -> d_out
}

// Round 13
// 93.698 us; speedup vs baseline: 6.2663x; 1.8526x over previous
//
#include <hip/hip_runtime.h>
#include <hip/hip_fp16.h>

#define CNUM 29
#define HH 256
#define WW 256
#define BB 2
#define KK 7
#define HALO 3
#define TX 32
#define TY 4
#define LW (TX + 2*HALO)   // 38
#define LH (TY + 2*HALO)   // 10
#define NPIX (LH*LW)       // 380
#define HWP (HH*WW)        // 65536

// 1-D normalized Gaussian, sigma=3.0, K=7 (exp(-d^2/18)/sum)
__device__ constexpr float GW[KK] = {
    0.106287146f, 0.140321912f, 0.165770643f, 0.175240699f,
    0.165770643f, 0.140321912f, 0.106287146f};

__device__ __forceinline__ unsigned packh2(float a, float b) {
    __half2 h = __floats2half2_rn(a, b);
    return *reinterpret_cast<unsigned*>(&h);
}
__device__ __forceinline__ float2 unpkh2(unsigned u) {
    __half2 h = *reinterpret_cast<__half2*>(&u);
    return __half22float2(h);
}

// One CRF iteration (round-8 structure restored; weight caching abandoned).
// 256 threads per 32x4 tile, tap-split: A-half (tid<128, epilogue owner) does
// kernel rows 4-6 (21 taps), B-half rows 0-3 (28 taps); partials joined via
// LDS [c][lid] aliasing s_q4 after taps. Weights recomputed inline from img
// every iteration (per-pixel bilateral -> no MFMA, no caching). img LDS split
// as float2+float planes: per tap 1x ds_read_b64 (2-way, free) + 1x b32
// instead of 3x b32. Global q fp16 channel-last [pix][4 x uint4]; uh = packed
// -unary fp16 from FIRST. Blocks XCD-chunk swizzled (bijective, 1024%8==0).
template <bool FIRST, bool LAST>
__global__ __launch_bounds__(256) void crf_iter(const float* __restrict__ unary,
                                                const float* __restrict__ img,
                                                const uint4* __restrict__ qin,
                                                uint4* __restrict__ qout,
                                                uint4* __restrict__ uh,
                                                float* __restrict__ outf) {
    __shared__ uint4  s_q4[NPIX * 4];     // 24,320 B; aliased as partial[29][128]
    __shared__ float2 s_im2[NPIX];        //  3,040 B (img ch0,ch1)
    __shared__ float  s_imz[NPIX];        //  1,520 B (img ch2)

    const int tid = threadIdx.x;
    const bool isA = tid < 128;           // wave-uniform half; A = epilogue owner
    const int lid = tid & 127;
    const int tx = lid & (TX - 1);
    const int ty = lid >> 5;              // 0..3

    // XCD-chunked bijective swizzle: dispatch-consecutive blocks (round-robin
    // across XCDs) map to 128-tile contiguous slabs per XCD -> halo L2 hits.
    const int flat = (blockIdx.z << 9) | (blockIdx.y << 3) | blockIdx.x;  // 0..1023
    const int sid  = ((flat & 7) << 7) | (flat >> 3);
    const int b    = sid >> 9;
    const int rem  = sid & 511;
    const int by   = (rem >> 3) * TY;
    const int bx   = (rem & 7) * TX;
    const int pix  = (by + ty) * WW + (bx + tx);

    const float* ubase = unary + (size_t)b * CNUM * HWP;
    const float* imgb  = img + (size_t)b * 3 * HWP;

    // ---- stage: img (float2+float planes) + q (fp16 chunks, XOR-swizzled) ----
    if (FIRST) {
        for (int t = tid; t < NPIX; t += 256) {
            int r = t / LW, cc = t - r * LW;
            int gy = by + r - HALO, gx = bx + cc - HALO;
            bool ok = (gy >= 0) & (gy < HH) & (gx >= 0) & (gx < WW);
            int goff = ok ? gy * WW + gx : 0;
            float i0 = imgb[goff], i1 = imgb[HWP + goff], i2 = imgb[2 * HWP + goff];
            if (!ok) { i0 = 0.f; i1 = 0.f; i2 = 0.f; }
            float2 v2; v2.x = i0; v2.y = i1;
            s_im2[t] = v2; s_imz[t] = i2;

            float nu[CNUM];
            float mm = -1e30f;
#pragma unroll
            for (int c = 0; c < CNUM; ++c) {
                nu[c] = -ubase[(size_t)c * HWP + goff];
                mm = fmaxf(mm, nu[c]);
            }
            bool interior = (r >= HALO) & (r < LH - HALO) & (cc >= HALO) & (cc < LW - HALO);
            if (interior) {  // pre-pack -unary fp16 (each pixel owned by one block)
                uint4* up = uh + ((size_t)b * HWP + goff) * 4;
                uint4 u0, u1, u2, u3;
                u0.x = packh2(nu[0],  nu[1]);  u0.y = packh2(nu[2],  nu[3]);
                u0.z = packh2(nu[4],  nu[5]);  u0.w = packh2(nu[6],  nu[7]);
                u1.x = packh2(nu[8],  nu[9]);  u1.y = packh2(nu[10], nu[11]);
                u1.z = packh2(nu[12], nu[13]); u1.w = packh2(nu[14], nu[15]);
                u2.x = packh2(nu[16], nu[17]); u2.y = packh2(nu[18], nu[19]);
                u2.z = packh2(nu[20], nu[21]); u2.w = packh2(nu[22], nu[23]);
                u3.x = packh2(nu[24], nu[25]); u3.y = packh2(nu[26], nu[27]);
                u3.z = packh2(nu[28], 0.f);    u3.w = 0u;
                up[0] = u0; up[1] = u1; up[2] = u2; up[3] = u3;
            }
            float ss = 0.f;
            float v[CNUM];
#pragma unroll
            for (int c = 0; c < CNUM; ++c) { v[c] = __expf(nu[c] - mm); ss += v[c]; }
            float inv = ok ? 1.f / ss : 0.f;
#pragma unroll
            for (int c = 0; c < CNUM; ++c) v[c] *= inv;
            const int swz = (t >> 1) & 3;
            uint4 p0, p1, p2, p3;
            p0.x = packh2(v[0],  v[1]);  p0.y = packh2(v[2],  v[3]);
            p0.z = packh2(v[4],  v[5]);  p0.w = packh2(v[6],  v[7]);
            p1.x = packh2(v[8],  v[9]);  p1.y = packh2(v[10], v[11]);
            p1.z = packh2(v[12], v[13]); p1.w = packh2(v[14], v[15]);
            p2.x = packh2(v[16], v[17]); p2.y = packh2(v[18], v[19]);
            p2.z = packh2(v[20], v[21]); p2.w = packh2(v[22], v[23]);
            p3.x = packh2(v[24], v[25]); p3.y = packh2(v[26], v[27]);
            p3.z = packh2(v[28], 0.f);   p3.w = 0u;
            s_q4[t * 4 + (0 ^ swz)] = p0;
            s_q4[t * 4 + (1 ^ swz)] = p1;
            s_q4[t * 4 + (2 ^ swz)] = p2;
            s_q4[t * 4 + (3 ^ swz)] = p3;
        }
    } else {
        // two staging rounds; all global loads issued before LDS writes
        int t = tid;
        int r = t / LW, cc = t - r * LW;
        int gy = by + r - HALO, gx = bx + cc - HALO;
        bool ok = (gy >= 0) & (gy < HH) & (gx >= 0) & (gx < WW);
        int goff = ok ? gy * WW + gx : 0;
        float i0 = imgb[goff], i1 = imgb[HWP + goff], i2 = imgb[2 * HWP + goff];
        const uint4* qp = qin + ((size_t)b * HWP + goff) * 4;
        uint4 p0 = qp[0], p1 = qp[1], p2 = qp[2], p3 = qp[3];

        int t2 = tid + 256;
        bool has2 = t2 < NPIX;
        int r2 = t2 / LW, cc2 = t2 - r2 * LW;
        int gy2 = by + r2 - HALO, gx2 = bx + cc2 - HALO;
        bool ok2 = has2 & (gy2 >= 0) & (gy2 < HH) & (gx2 >= 0) & (gx2 < WW);
        int goff2 = ok2 ? gy2 * WW + gx2 : 0;
        float j0 = 0.f, j1 = 0.f, j2 = 0.f;
        uint4 s0, s1, s2, s3;
        if (has2) {
            j0 = imgb[goff2]; j1 = imgb[HWP + goff2]; j2 = imgb[2 * HWP + goff2];
            const uint4* qp2 = qin + ((size_t)b * HWP + goff2) * 4;
            s0 = qp2[0]; s1 = qp2[1]; s2 = qp2[2]; s3 = qp2[3];
        }
        if (!ok) {
            i0 = 0.f; i1 = 0.f; i2 = 0.f;
            p0.x = p0.y = p0.z = p0.w = 0u; p1.x = p1.y = p1.z = p1.w = 0u;
            p2.x = p2.y = p2.z = p2.w = 0u; p3.x = p3.y = p3.z = p3.w = 0u;
        }
        float2 v2; v2.x = i0; v2.y = i1;
        s_im2[t] = v2; s_imz[t] = i2;
        const int swz = (t >> 1) & 3;
        s_q4[t * 4 + (0 ^ swz)] = p0;
        s_q4[t * 4 + (1 ^ swz)] = p1;
        s_q4[t * 4 + (2 ^ swz)] = p2;
        s_q4[t * 4 + (3 ^ swz)] = p3;
        if (has2) {
            if (!ok2) {
                j0 = 0.f; j1 = 0.f; j2 = 0.f;
                s0.x = s0.y = s0.z = s0.w = 0u; s1.x = s1.y = s1.z = s1.w = 0u;
                s2.x = s2.y = s2.z = s2.w = 0u; s3.x = s3.y = s3.z = s3.w = 0u;
            }
            float2 w2; w2.x = j0; w2.y = j1;
            s_im2[t2] = w2; s_imz[t2] = j2;
            const int swz2 = (t2 >> 1) & 3;
            s_q4[t2 * 4 + (0 ^ swz2)] = s0;
            s_q4[t2 * 4 + (1 ^ swz2)] = s1;
            s_q4[t2 * 4 + (2 ^ swz2)] = s2;
            s_q4[t2 * 4 + (3 ^ swz2)] = s3;
        }
    }
    __syncthreads();

    // ---- tap phase (kernel rows split between halves) ----
    const int tc = (ty + HALO) * LW + (tx + HALO);
    const float2 cv = s_im2[tc];
    const float c0 = cv.x;
    const float c1 = cv.y;
    const float c2 = s_imz[tc];

    float acc[CNUM];
#pragma unroll
    for (int c = 0; c < CNUM; ++c) acc[c] = 0.f;

#define TAP_BODY(ii)                                                        \
    {                                                                       \
        const int t = (ty + (ii)) * LW + (tx + j);                          \
        float2 iv = s_im2[t];                                               \
        float d0 = iv.x - c0;                                               \
        float d1 = iv.y - c1;                                               \
        float d2 = s_imz[t] - c2;                                           \
        float dsq = d0 * d0 + d1 * d1 + d2 * d2;                            \
        float w = (GW[(ii)] * GW[j]) * (3.0f + 10.0f * __expf(dsq * -0.005f)); \
        const int t4 = t * 4;                                               \
        const int swz = (t >> 1) & 3;                                       \
        uint4 q0 = s_q4[t4 + (0 ^ swz)];                                    \
        uint4 q1 = s_q4[t4 + (1 ^ swz)];                                    \
        uint4 q2 = s_q4[t4 + (2 ^ swz)];                                    \
        uint4 q3 = s_q4[t4 + (3 ^ swz)];                                    \
        const unsigned* u0 = &q0.x;                                         \
        const unsigned* u1 = &q1.x;                                         \
        const unsigned* u2 = &q2.x;                                         \
        _Pragma("unroll")                                                   \
        for (int k = 0; k < 4; ++k) {                                       \
            float2 f = unpkh2(u0[k]);                                       \
            acc[2 * k]     += w * f.x;                                      \
            acc[2 * k + 1] += w * f.y;                                      \
        }                                                                   \
        _Pragma("unroll")                                                   \
        for (int k = 0; k < 4; ++k) {                                       \
            float2 f = unpkh2(u1[k]);                                       \
            acc[8 + 2 * k]     += w * f.x;                                  \
            acc[8 + 2 * k + 1] += w * f.y;                                  \
        }                                                                   \
        _Pragma("unroll")                                                   \
        for (int k = 0; k < 4; ++k) {                                       \
            float2 f = unpkh2(u2[k]);                                       \
            acc[16 + 2 * k]     += w * f.x;                                 \
            acc[16 + 2 * k + 1] += w * f.y;                                 \
        }                                                                   \
        {                                                                   \
            float2 f = unpkh2(q3.x);                                        \
            acc[24] += w * f.x; acc[25] += w * f.y;                         \
            f = unpkh2(q3.y);                                               \
            acc[26] += w * f.x; acc[27] += w * f.y;                         \
            f = unpkh2(q3.z);                                               \
            acc[28] += w * f.x;                                             \
        }                                                                   \
    }

    if (isA) {   // epilogue owner: fewer taps (rows 4-6, 21 taps)
#pragma unroll
        for (int i = 4; i < KK; ++i)
#pragma unroll
            for (int j = 0; j < KK; ++j) TAP_BODY(i)
    } else {     // rows 0-3, 28 taps + partial write
#pragma unroll
        for (int i = 0; i < 4; ++i)
#pragma unroll
            for (int j = 0; j < KK; ++j) TAP_BODY(i)
    }
#undef TAP_BODY

    // ---- join partials: B writes [c][lid], A adds ----
    __syncthreads();                       // all s_q4 tap reads complete
    float* s_part = reinterpret_cast<float*>(s_q4);   // 29*128*4 = 14,848 B fits
    if (!isA) {
#pragma unroll
        for (int c = 0; c < CNUM; ++c) s_part[c * 128 + lid] = acc[c];
    }
    __syncthreads();

    if (isA) {
        float l[CNUM];
        if (FIRST) {
#pragma unroll
            for (int c = 0; c < CNUM; ++c)
                l[c] = acc[c] + s_part[c * 128 + lid] - ubase[(size_t)c * HWP + pix];
        } else {
            const uint4* up = uh + ((size_t)b * HWP + pix) * 4;
            uint4 n0 = up[0], n1 = up[1], n2 = up[2], n3 = up[3];
            const unsigned* w0 = &n0.x;
            const unsigned* w1 = &n1.x;
            const unsigned* w2 = &n2.x;
            float nu[CNUM];
#pragma unroll
            for (int k = 0; k < 4; ++k) {
                float2 f = unpkh2(w0[k]); nu[2 * k] = f.x; nu[2 * k + 1] = f.y;
            }
#pragma unroll
            for (int k = 0; k < 4; ++k) {
                float2 f = unpkh2(w1[k]); nu[8 + 2 * k] = f.x; nu[8 + 2 * k + 1] = f.y;
            }
#pragma unroll
            for (int k = 0; k < 4; ++k) {
                float2 f = unpkh2(w2[k]); nu[16 + 2 * k] = f.x; nu[16 + 2 * k + 1] = f.y;
            }
            { float2 f = unpkh2(n3.x); nu[24] = f.x; nu[25] = f.y; }
            { float2 f = unpkh2(n3.y); nu[26] = f.x; nu[27] = f.y; }
            { float2 f = unpkh2(n3.z); nu[28] = f.x; }
#pragma unroll
            for (int c = 0; c < CNUM; ++c)
                l[c] = acc[c] + s_part[c * 128 + lid] + nu[c];
        }
        float m = l[0];
#pragma unroll
        for (int c = 1; c < CNUM; ++c) m = fmaxf(m, l[c]);
        float ss = 0.f;
#pragma unroll
        for (int c = 0; c < CNUM; ++c) { l[c] = __expf(l[c] - m); ss += l[c]; }
        float inv = 1.0f / ss;

        if (LAST) {
            float* qo = outf + (size_t)b * CNUM * HWP + pix;
#pragma unroll
            for (int c = 0; c < CNUM; ++c) qo[(size_t)c * HWP] = l[c] * inv;
        } else {
            uint4 p0, p1, p2, p3;
            p0.x = packh2(l[0] * inv,  l[1] * inv);
            p0.y = packh2(l[2] * inv,  l[3] * inv);
            p0.z = packh2(l[4] * inv,  l[5] * inv);
            p0.w = packh2(l[6] * inv,  l[7] * inv);
            p1.x = packh2(l[8] * inv,  l[9] * inv);
            p1.y = packh2(l[10] * inv, l[11] * inv);
            p1.z = packh2(l[12] * inv, l[13] * inv);
            p1.w = packh2(l[14] * inv, l[15] * inv);
            p2.x = packh2(l[16] * inv, l[17] * inv);
            p2.y = packh2(l[18] * inv, l[19] * inv);
            p2.z = packh2(l[20] * inv, l[21] * inv);
            p2.w = packh2(l[22] * inv, l[23] * inv);
            p3.x = packh2(l[24] * inv, l[25] * inv);
            p3.y = packh2(l[26] * inv, l[27] * inv);
            p3.z = packh2(l[28] * inv, 0.f);
            p3.w = 0u;
            uint4* qo = qout + ((size_t)b * HWP + pix) * 4;
            qo[0] = p0; qo[1] = p1; qo[2] = p2; qo[3] = p3;
        }
    }
}

extern "C" void kernel_launch(void* const* d_in, const int* in_sizes, int n_in,
                              void* d_out, int out_size, void* d_ws, size_t ws_size,
                              hipStream_t stream) {
    const float* unary = (const float*)d_in[0];
    const float* img   = (const float*)d_in[1];
    // ws: qA (8.39MB) | qB (8.39MB) | uh (8.39MB) = 25.2 MB
    const size_t QBYTES = (size_t)BB * HWP * 64;
    uint4* qA = (uint4*)d_ws;
    uint4* qB = (uint4*)((char*)d_ws + QBYTES);
    uint4* uh = (uint4*)((char*)d_ws + 2 * QBYTES);
    float* outf = (float*)d_out;

    dim3 grid(WW / TX, HH / TY, BB);   // (8, 64, 2) = 1024 blocks
    crf_iter<true,  false><<<grid, 256, 0, stream>>>(unary, img, qB, qA, uh, outf); // i1 -> qA
    crf_iter<false, false><<<grid, 256, 0, stream>>>(unary, img, qA, qB, uh, outf); // i2
    crf_iter<false, false><<<grid, 256, 0, stream>>>(unary, img, qB, qA, uh, outf); // i3
    crf_iter<false, false><<<grid, 256, 0, stream>>>(unary, img, qA, qB, uh, outf); // i4
    crf_iter<false, true ><<<grid, 256, 0, stream>>>(unary, img, qB, qA, uh, outf); // i5 -> d_out
}

// Round 14
// 90.158 us; speedup vs baseline: 6.5123x; 1.0393x over previous
//
#include <hip/hip_runtime.h>
#include <hip/hip_fp16.h>

#define CNUM 29
#define HH 256
#define WW 256
#define BB 2
#define KK 7
#define HALO 3
#define TX 32
#define TY 4
#define LW (TX + 2*HALO)   // 38
#define LH (TY + 2*HALO)   // 10
#define NPIX (LH*LW)       // 380
#define HWP (HH*WW)        // 65536

// 1-D normalized Gaussian, sigma=3.0, K=7 (exp(-d^2/18)/sum)
__device__ constexpr float GW[KK] = {
    0.106287146f, 0.140321912f, 0.165770643f, 0.175240699f,
    0.165770643f, 0.140321912f, 0.106287146f};

__device__ __forceinline__ unsigned packh2(float a, float b) {
    __half2 h = __floats2half2_rn(a, b);
    return *reinterpret_cast<unsigned*>(&h);
}
__device__ __forceinline__ float2 unpkh2(unsigned u) {
    __half2 h = *reinterpret_cast<__half2*>(&u);
    return __half22float2(h);
}

// One CRF iteration. 256 threads per 32x4 tile, tap-split (A: rows 4-6 = 21
// taps, B: rows 0-3 = 28 taps). EPILOGUE IS SPLIT TOO: A owns ch 0-15
// (chunks 0,1), B owns ch 16-28 (chunks 2,3); partials cross-written in
// s_part; softmax is NO-MAX (logits bounded ~18 -> exp safe in f32) with a
// single sum exchange via s_red; B relays its packed chunks through LDS so
// the global store stays one-thread-per-64B-line (r13-proven). img LDS as
// float2+float planes. Global q fp16 channel-last [pix][4 x uint4]; uh =
// packed -unary fp16 from FIRST. Blocks XCD-chunk swizzled (bijective).
template <bool FIRST, bool LAST>
__global__ __launch_bounds__(256) void crf_iter(const float* __restrict__ unary,
                                                const float* __restrict__ img,
                                                const uint4* __restrict__ qin,
                                                uint4* __restrict__ qout,
                                                uint4* __restrict__ uh,
                                                float* __restrict__ outf) {
    __shared__ uint4  s_q4[NPIX * 4];     // 24,320 B; aliased: partial[29][128], relay
    __shared__ float2 s_im2[NPIX];        //  3,040 B (img ch0,ch1)
    __shared__ float  s_imz[NPIX];        //  1,520 B (img ch2)
    __shared__ float  s_red[2][128];      //  1,024 B (sum exchange)

    const int tid = threadIdx.x;
    const bool isA = tid < 128;           // wave-uniform half
    const int lid = tid & 127;
    const int tx = lid & (TX - 1);
    const int ty = lid >> 5;              // 0..3

    // XCD-chunked bijective swizzle (1024 % 8 == 0)
    const int flat = (blockIdx.z << 9) | (blockIdx.y << 3) | blockIdx.x;  // 0..1023
    const int sid  = ((flat & 7) << 7) | (flat >> 3);
    const int b    = sid >> 9;
    const int rem  = sid & 511;
    const int by   = (rem >> 3) * TY;
    const int bx   = (rem & 7) * TX;
    const int pix  = (by + ty) * WW + (bx + tx);

    const float* ubase = unary + (size_t)b * CNUM * HWP;
    const float* imgb  = img + (size_t)b * 3 * HWP;

    // ---- stage: img (float2+float planes) + q (fp16 chunks, XOR-swizzled) ----
    if (FIRST) {
        for (int t = tid; t < NPIX; t += 256) {
            int r = t / LW, cc = t - r * LW;
            int gy = by + r - HALO, gx = bx + cc - HALO;
            bool ok = (gy >= 0) & (gy < HH) & (gx >= 0) & (gx < WW);
            int goff = ok ? gy * WW + gx : 0;
            float i0 = imgb[goff], i1 = imgb[HWP + goff], i2 = imgb[2 * HWP + goff];
            if (!ok) { i0 = 0.f; i1 = 0.f; i2 = 0.f; }
            float2 v2; v2.x = i0; v2.y = i1;
            s_im2[t] = v2; s_imz[t] = i2;

            float nu[CNUM];
#pragma unroll
            for (int c = 0; c < CNUM; ++c) nu[c] = -ubase[(size_t)c * HWP + goff];
            bool interior = (r >= HALO) & (r < LH - HALO) & (cc >= HALO) & (cc < LW - HALO);
            if (interior) {  // pre-pack -unary fp16 (each pixel owned by one block)
                uint4* up = uh + ((size_t)b * HWP + goff) * 4;
                uint4 u0, u1, u2, u3;
                u0.x = packh2(nu[0],  nu[1]);  u0.y = packh2(nu[2],  nu[3]);
                u0.z = packh2(nu[4],  nu[5]);  u0.w = packh2(nu[6],  nu[7]);
                u1.x = packh2(nu[8],  nu[9]);  u1.y = packh2(nu[10], nu[11]);
                u1.z = packh2(nu[12], nu[13]); u1.w = packh2(nu[14], nu[15]);
                u2.x = packh2(nu[16], nu[17]); u2.y = packh2(nu[18], nu[19]);
                u2.z = packh2(nu[20], nu[21]); u2.w = packh2(nu[22], nu[23]);
                u3.x = packh2(nu[24], nu[25]); u3.y = packh2(nu[26], nu[27]);
                u3.z = packh2(nu[28], 0.f);    u3.w = 0u;
                up[0] = u0; up[1] = u1; up[2] = u2; up[3] = u3;
            }
            // no-max softmax: -unary <= ~5.5 -> exp <= ~250, f32-safe
            float ss = 0.f;
            float v[CNUM];
#pragma unroll
            for (int c = 0; c < CNUM; ++c) { v[c] = __expf(nu[c]); ss += v[c]; }
            float inv = ok ? 1.f / ss : 0.f;
#pragma unroll
            for (int c = 0; c < CNUM; ++c) v[c] *= inv;
            const int swz = (t >> 1) & 3;
            uint4 p0, p1, p2, p3;
            p0.x = packh2(v[0],  v[1]);  p0.y = packh2(v[2],  v[3]);
            p0.z = packh2(v[4],  v[5]);  p0.w = packh2(v[6],  v[7]);
            p1.x = packh2(v[8],  v[9]);  p1.y = packh2(v[10], v[11]);
            p1.z = packh2(v[12], v[13]); p1.w = packh2(v[14], v[15]);
            p2.x = packh2(v[16], v[17]); p2.y = packh2(v[18], v[19]);
            p2.z = packh2(v[20], v[21]); p2.w = packh2(v[22], v[23]);
            p3.x = packh2(v[24], v[25]); p3.y = packh2(v[26], v[27]);
            p3.z = packh2(v[28], 0.f);   p3.w = 0u;
            s_q4[t * 4 + (0 ^ swz)] = p0;
            s_q4[t * 4 + (1 ^ swz)] = p1;
            s_q4[t * 4 + (2 ^ swz)] = p2;
            s_q4[t * 4 + (3 ^ swz)] = p3;
        }
    } else {
        // two staging rounds; all global loads issued before LDS writes
        int t = tid;
        int r = t / LW, cc = t - r * LW;
        int gy = by + r - HALO, gx = bx + cc - HALO;
        bool ok = (gy >= 0) & (gy < HH) & (gx >= 0) & (gx < WW);
        int goff = ok ? gy * WW + gx : 0;
        float i0 = imgb[goff], i1 = imgb[HWP + goff], i2 = imgb[2 * HWP + goff];
        const uint4* qp = qin + ((size_t)b * HWP + goff) * 4;
        uint4 p0 = qp[0], p1 = qp[1], p2 = qp[2], p3 = qp[3];

        int t2 = tid + 256;
        bool has2 = t2 < NPIX;
        int r2 = t2 / LW, cc2 = t2 - r2 * LW;
        int gy2 = by + r2 - HALO, gx2 = bx + cc2 - HALO;
        bool ok2 = has2 & (gy2 >= 0) & (gy2 < HH) & (gx2 >= 0) & (gx2 < WW);
        int goff2 = ok2 ? gy2 * WW + gx2 : 0;
        float j0 = 0.f, j1 = 0.f, j2 = 0.f;
        uint4 s0, s1, s2, s3;
        if (has2) {
            j0 = imgb[goff2]; j1 = imgb[HWP + goff2]; j2 = imgb[2 * HWP + goff2];
            const uint4* qp2 = qin + ((size_t)b * HWP + goff2) * 4;
            s0 = qp2[0]; s1 = qp2[1]; s2 = qp2[2]; s3 = qp2[3];
        }
        if (!ok) {
            i0 = 0.f; i1 = 0.f; i2 = 0.f;
            p0.x = p0.y = p0.z = p0.w = 0u; p1.x = p1.y = p1.z = p1.w = 0u;
            p2.x = p2.y = p2.z = p2.w = 0u; p3.x = p3.y = p3.z = p3.w = 0u;
        }
        float2 v2; v2.x = i0; v2.y = i1;
        s_im2[t] = v2; s_imz[t] = i2;
        const int swz = (t >> 1) & 3;
        s_q4[t * 4 + (0 ^ swz)] = p0;
        s_q4[t * 4 + (1 ^ swz)] = p1;
        s_q4[t * 4 + (2 ^ swz)] = p2;
        s_q4[t * 4 + (3 ^ swz)] = p3;
        if (has2) {
            if (!ok2) {
                j0 = 0.f; j1 = 0.f; j2 = 0.f;
                s0.x = s0.y = s0.z = s0.w = 0u; s1.x = s1.y = s1.z = s1.w = 0u;
                s2.x = s2.y = s2.z = s2.w = 0u; s3.x = s3.y = s3.z = s3.w = 0u;
            }
            float2 w2; w2.x = j0; w2.y = j1;
            s_im2[t2] = w2; s_imz[t2] = j2;
            const int swz2 = (t2 >> 1) & 3;
            s_q4[t2 * 4 + (0 ^ swz2)] = s0;
            s_q4[t2 * 4 + (1 ^ swz2)] = s1;
            s_q4[t2 * 4 + (2 ^ swz2)] = s2;
            s_q4[t2 * 4 + (3 ^ swz2)] = s3;
        }
    }
    __syncthreads();

    // ---- tap phase (kernel rows split between halves) ----
    const int tc = (ty + HALO) * LW + (tx + HALO);
    const float2 cv = s_im2[tc];
    const float c0 = cv.x;
    const float c1 = cv.y;
    const float c2 = s_imz[tc];

    float acc[CNUM];
#pragma unroll
    for (int c = 0; c < CNUM; ++c) acc[c] = 0.f;

#define TAP_BODY(ii)                                                        \
    {                                                                       \
        const int t = (ty + (ii)) * LW + (tx + j);                          \
        float2 iv = s_im2[t];                                               \
        float d0 = iv.x - c0;                                               \
        float d1 = iv.y - c1;                                               \
        float d2 = s_imz[t] - c2;                                           \
        float dsq = d0 * d0 + d1 * d1 + d2 * d2;                            \
        float w = (GW[(ii)] * GW[j]) * (3.0f + 10.0f * __expf(dsq * -0.005f)); \
        const int t4 = t * 4;                                               \
        const int swz = (t >> 1) & 3;                                       \
        uint4 q0 = s_q4[t4 + (0 ^ swz)];                                    \
        uint4 q1 = s_q4[t4 + (1 ^ swz)];                                    \
        uint4 q2 = s_q4[t4 + (2 ^ swz)];                                    \
        uint4 q3 = s_q4[t4 + (3 ^ swz)];                                    \
        const unsigned* u0 = &q0.x;                                         \
        const unsigned* u1 = &q1.x;                                         \
        const unsigned* u2 = &q2.x;                                         \
        _Pragma("unroll")                                                   \
        for (int k = 0; k < 4; ++k) {                                       \
            float2 f = unpkh2(u0[k]);                                       \
            acc[2 * k]     += w * f.x;                                      \
            acc[2 * k + 1] += w * f.y;                                      \
        }                                                                   \
        _Pragma("unroll")                                                   \
        for (int k = 0; k < 4; ++k) {                                       \
            float2 f = unpkh2(u1[k]);                                       \
            acc[8 + 2 * k]     += w * f.x;                                  \
            acc[8 + 2 * k + 1] += w * f.y;                                  \
        }                                                                   \
        _Pragma("unroll")                                                   \
        for (int k = 0; k < 4; ++k) {                                       \
            float2 f = unpkh2(u2[k]);                                       \
            acc[16 + 2 * k]     += w * f.x;                                 \
            acc[16 + 2 * k + 1] += w * f.y;                                 \
        }                                                                   \
        {                                                                   \
            float2 f = unpkh2(q3.x);                                        \
            acc[24] += w * f.x; acc[25] += w * f.y;                         \
            f = unpkh2(q3.y);                                               \
            acc[26] += w * f.x; acc[27] += w * f.y;                         \
            f = unpkh2(q3.z);                                               \
            acc[28] += w * f.x;                                             \
        }                                                                   \
    }

    __builtin_amdgcn_s_setprio(1);
    if (isA) {   // rows 4-6 (21 taps)
#pragma unroll
        for (int i = 4; i < KK; ++i)
#pragma unroll
            for (int j = 0; j < KK; ++j) TAP_BODY(i)
    } else {     // rows 0-3 (28 taps)
#pragma unroll
        for (int i = 0; i < 4; ++i)
#pragma unroll
            for (int j = 0; j < KK; ++j) TAP_BODY(i)
    }
    __builtin_amdgcn_s_setprio(0);
#undef TAP_BODY

    // ---- cross-write partials: B -> ch 0-15 (A's), A -> ch 16-28 (B's) ----
    __syncthreads();                       // all s_q4 tap reads complete
    float* s_part = reinterpret_cast<float*>(s_q4);   // 29*128*4 = 14,848 B
    if (isA) {
#pragma unroll
        for (int c = 16; c < CNUM; ++c) s_part[c * 128 + lid] = acc[c];
    } else {
#pragma unroll
        for (int c = 0; c < 16; ++c) s_part[c * 128 + lid] = acc[c];
    }
    __syncthreads();

    // ---- split epilogue: A owns ch 0-15, B owns ch 16-28; no-max softmax ----
    float l[16];
    float ss_loc = 0.f;
    if (isA) {
        float nu[16];
        if (FIRST) {
#pragma unroll
            for (int c = 0; c < 16; ++c) nu[c] = -ubase[(size_t)c * HWP + pix];
        } else {
            const uint4* up = uh + ((size_t)b * HWP + pix) * 4;
            uint4 n0 = up[0], n1 = up[1];
            const unsigned* w0 = &n0.x;
            const unsigned* w1 = &n1.x;
#pragma unroll
            for (int k = 0; k < 4; ++k) {
                float2 f = unpkh2(w0[k]); nu[2 * k] = f.x; nu[2 * k + 1] = f.y;
            }
#pragma unroll
            for (int k = 0; k < 4; ++k) {
                float2 f = unpkh2(w1[k]); nu[8 + 2 * k] = f.x; nu[8 + 2 * k + 1] = f.y;
            }
        }
#pragma unroll
        for (int c = 0; c < 16; ++c) {
            l[c] = __expf(acc[c] + s_part[c * 128 + lid] + nu[c]);
            ss_loc += l[c];
        }
    } else {
        float nu[13];
        if (FIRST) {
#pragma unroll
            for (int c = 0; c < 13; ++c) nu[c] = -ubase[(size_t)(16 + c) * HWP + pix];
        } else {
            const uint4* up = uh + ((size_t)b * HWP + pix) * 4;
            uint4 n2 = up[2], n3 = up[3];
            const unsigned* w2 = &n2.x;
#pragma unroll
            for (int k = 0; k < 4; ++k) {
                float2 f = unpkh2(w2[k]); nu[2 * k] = f.x; nu[2 * k + 1] = f.y;
            }
            { float2 f = unpkh2(n3.x); nu[8]  = f.x; nu[9]  = f.y; }
            { float2 f = unpkh2(n3.y); nu[10] = f.x; nu[11] = f.y; }
            { float2 f = unpkh2(n3.z); nu[12] = f.x; }
        }
#pragma unroll
        for (int c = 0; c < 13; ++c) {
            l[c] = __expf(acc[16 + c] + s_part[(16 + c) * 128 + lid] + nu[c]);
            ss_loc += l[c];
        }
    }
    s_red[isA ? 0 : 1][lid] = ss_loc;
    __syncthreads();
    const float inv = 1.0f / (s_red[0][lid] + s_red[1][lid]);

    if (LAST) {
        float* qo = outf + (size_t)b * CNUM * HWP + pix;
        if (isA) {
#pragma unroll
            for (int c = 0; c < 16; ++c) qo[(size_t)c * HWP] = l[c] * inv;
        } else {
#pragma unroll
            for (int c = 0; c < 13; ++c) qo[(size_t)(16 + c) * HWP] = l[c] * inv;
        }
    } else {
        uint4* s_xf = reinterpret_cast<uint4*>(s_q4);   // relay (region dead)
        if (!isA) {
            uint4 p2, p3;
            p2.x = packh2(l[0] * inv,  l[1] * inv);    // ch16,17
            p2.y = packh2(l[2] * inv,  l[3] * inv);
            p2.z = packh2(l[4] * inv,  l[5] * inv);
            p2.w = packh2(l[6] * inv,  l[7] * inv);
            p3.x = packh2(l[8] * inv,  l[9] * inv);
            p3.y = packh2(l[10] * inv, l[11] * inv);
            p3.z = packh2(l[12] * inv, 0.f);           // ch28
            p3.w = 0u;
            s_xf[lid * 2 + 0] = p2;
            s_xf[lid * 2 + 1] = p3;
        }
        __syncthreads();
        if (isA) {
            uint4 p0, p1;
            p0.x = packh2(l[0] * inv,  l[1] * inv);
            p0.y = packh2(l[2] * inv,  l[3] * inv);
            p0.z = packh2(l[4] * inv,  l[5] * inv);
            p0.w = packh2(l[6] * inv,  l[7] * inv);
            p1.x = packh2(l[8] * inv,  l[9] * inv);
            p1.y = packh2(l[10] * inv, l[11] * inv);
            p1.z = packh2(l[12] * inv, l[13] * inv);
            p1.w = packh2(l[14] * inv, l[15] * inv);
            uint4 p2 = s_xf[lid * 2 + 0];
            uint4 p3 = s_xf[lid * 2 + 1];
            uint4* qo = qout + ((size_t)b * HWP + pix) * 4;
            qo[0] = p0; qo[1] = p1; qo[2] = p2; qo[3] = p3;
        }
    }
}

extern "C" void kernel_launch(void* const* d_in, const int* in_sizes, int n_in,
                              void* d_out, int out_size, void* d_ws, size_t ws_size,
                              hipStream_t stream) {
    const float* unary = (const float*)d_in[0];
    const float* img   = (const float*)d_in[1];
    // ws: qA (8.39MB) | qB (8.39MB) | uh (8.39MB) = 25.2 MB
    const size_t QBYTES = (size_t)BB * HWP * 64;
    uint4* qA = (uint4*)d_ws;
    uint4* qB = (uint4*)((char*)d_ws + QBYTES);
    uint4* uh = (uint4*)((char*)d_ws + 2 * QBYTES);
    float* outf = (float*)d_out;

    dim3 grid(WW / TX, HH / TY, BB);   // (8, 64, 2) = 1024 blocks
    crf_iter<true,  false><<<grid, 256, 0, stream>>>(unary, img, qB, qA, uh, outf); // i1 -> qA
    crf_iter<false, false><<<grid, 256, 0, stream>>>(unary, img, qA, qB, uh, outf); // i2
    crf_iter<false, false><<<grid, 256, 0, stream>>>(unary, img, qB, qA, uh, outf); // i3
    crf_iter<false, false><<<grid, 256, 0, stream>>>(unary, img, qA, qB, uh, outf); // i4
    crf_iter<false, true ><<<grid, 256, 0, stream>>>(unary, img, qB, qA, uh, outf); // i5 -> d_out
}